// Round 12
// baseline (1727.441 us; speedup 1.0000x reference)
//
#include <hip/hip_runtime.h>
#include <math.h>

#define LR 0.001f

// Sizes
#define B   64
#define IN  2048
#define HID 512
#define OUT 128
#define NBLK 256
#define NTHR 512
#define NCOMP 64        // dedicated compute blocks (one per sample)

#define AQ __ATOMIC_ACQUIRE
#define RL __ATOMIC_RELEASE
#define RX __ATOMIC_RELAXED
#define SCP __HIP_MEMORY_SCOPE_AGENT

typedef float vf2 __attribute__((ext_vector_type(2)));
typedef float vf4 __attribute__((ext_vector_type(4)));

// coop ws layout (floats)
#define WS_ZPART 0                        // [64][8][512] = 262144
#define WS_GBW   (WS_ZPART + B*8*HID)     // [64][512]    = 32768
#define WS_Q     (WS_GBW + B*HID)         // queue ints
// fallback layout (separate path, fully rewritten before reads)
#define FQC    16
#define FWS_ZP    0
#define FWS_TANH  (FWS_ZP + B*FQC*HID)
#define FWS_ZOP   (FWS_TANH + B*HID)
#define FWS_GB    (FWS_ZOP + B*8*OUT)

// out layout (floats)
#define O_L2N   0
#define O_DW0   (B*OUT)
#define O_DB0   (O_DW0 + B*IN*HID)
#define O_DW1   (O_DB0 + B*HID)
#define O_DB1   (O_DW1 + B*HID*OUT)

struct Q {
    int fwd_claim;   // 0..512
    int upd_claim;   // 0..512
    int reserve;     // ready-list reservation
    int tail;        // committed ready samples
    int zcnt[B];     // fwd1 slabs done per sample
    int list[B];     // ready-list entries: b+1 (0 = empty)
};

// LDS layout (floats): [0..2047] reduce buf | [2048..2303] x stage |
// [2304..2815] sth | [2816..2943] sg2 | [2944..2951] sred
#define L_BUF  0
#define L_X    2048
#define L_STH  2304
#define L_G2   2816
#define L_RED  2944
#define L_TOT  2952

// ---- fwd1 item: z-partials for (b, slab s): 256 q-rows ----
__device__ __forceinline__ void do_fwd1(int f, const float* __restrict__ x,
                                        const float* __restrict__ W0,
                                        const float* __restrict__ dW0,
                                        float* __restrict__ zpart, Q* q,
                                        float* lds, int tid) {
    const int b = f >> 3, s = f & 7, q0 = s * 256;
    __syncthreads();
    if (tid < 256) lds[L_X + tid] = x[b * IN + q0 + tid];
    __syncthreads();
    const int sub = tid >> 7;                 // 0..3, 64 q each
    const int h = (tid & 127) << 2;
    const float* pW = W0 + (size_t)(q0 + sub * 64) * HID + h;
    const float* pD = dW0 + ((size_t)b * IN + q0 + sub * 64) * HID + h;
    const float* xs = lds + L_X + sub * 64;
    float4 acc = make_float4(0.f, 0.f, 0.f, 0.f);
    #pragma unroll 4
    for (int qi = 0; qi < 64; ++qi) {
        const float xv = xs[qi];
        const float4 w0 = *(const float4*)(pW + (size_t)qi * HID);
        const float4 dw = *(const float4*)(pD + (size_t)qi * HID);
        acc.x += xv * (w0.x + dw.x);
        acc.y += xv * (w0.y + dw.y);
        acc.z += xv * (w0.z + dw.z);
        acc.w += xv * (w0.w + dw.w);
    }
    *(float4*)(lds + L_BUF + sub * 512 + h) = acc;
    __syncthreads();
    if (sub == 0) {
        const float4 a1 = *(float4*)(lds + L_BUF + 512 + h);
        const float4 a2 = *(float4*)(lds + L_BUF + 1024 + h);
        const float4 a3 = *(float4*)(lds + L_BUF + 1536 + h);
        acc.x += a1.x + a2.x + a3.x;
        acc.y += a1.y + a2.y + a3.y;
        acc.z += a1.z + a2.z + a3.z;
        acc.w += a1.w + a2.w + a3.w;
        *(float4*)(zpart + ((size_t)b * 8 + s) * HID + h) = acc;
    }
    __syncthreads();
    __threadfence();
    if (tid == 0) __hip_atomic_fetch_add(&q->zcnt[b], 1, RL, SCP);
}

// ---- upd0 item: new_dW0 slab = dW0 - LR*x*gb (read L3-hot, NT write) ----
__device__ __forceinline__ void do_upd(int b, int s, const float* __restrict__ x,
                                       const float* __restrict__ dW0,
                                       const float* __restrict__ gbw,
                                       float* __restrict__ out_dW0,
                                       float* lds, int tid) {
    __syncthreads();
    lds[L_BUF + tid] = gbw[(size_t)b * HID + tid];
    if (tid < 256) lds[L_X + tid] = x[b * IN + s * 256 + tid];
    __syncthreads();
    const size_t base4 = ((size_t)b * IN + s * 256) * (HID / 4);
    const float4* src = (const float4*)dW0;
    vf4* dst = (vf4*)out_dW0;
    #pragma unroll 4
    for (int it = 0; it < 64; ++it) {
        const int i = it * NTHR + tid;
        const int ql = i >> 7, h4 = i & 127;
        const float4 dw = src[base4 + i];
        const float xv = lds[L_X + ql];
        const float4 g = *(const float4*)&lds[L_BUF + h4 * 4];
        vf4 o4;
        o4.x = dw.x - LR * xv * g.x;
        o4.y = dw.y - LR * xv * g.y;
        o4.z = dw.z - LR * xv * g.z;
        o4.w = dw.w - LR * xv * g.w;
        __builtin_nontemporal_store(o4, dst + base4 + i);
    }
}

// ---- per-sample compute: tanh + zo + stats + g2 + bwd1 + gb ----
__device__ __forceinline__ void do_compute(int b, const float* __restrict__ ut,
                                           const float* __restrict__ bias0,
                                           const float* __restrict__ W1,
                                           const float* __restrict__ bias1,
                                           const float* __restrict__ db0,
                                           const float* __restrict__ dW1,
                                           const float* __restrict__ db1,
                                           const float* __restrict__ zpart,
                                           float* __restrict__ gbw,
                                           float* __restrict__ out,
                                           Q* q, float* lds, int tid) {
    float* sth = lds + L_STH;
    float* sg2 = lds + L_G2;
    float* sred = lds + L_RED;
    // tanh(z + b0 + db0)
    {
        float zs = 0.f;
        const float* p = zpart + (size_t)b * 8 * HID + tid;
        #pragma unroll
        for (int k = 0; k < 8; ++k) zs += p[(size_t)k * HID];
        sth[tid] = tanhf(zs + bias0[tid] + db0[b * HID + tid]);
    }
    __syncthreads();
    // zo partials: (hc = tid>>7) x (o = tid&127), 128 h each
    {
        const int hc = tid >> 7, o = tid & 127;
        const float* pw = W1 + (size_t)(hc * 128) * OUT + o;
        const float* pd = dW1 + ((size_t)b * HID + hc * 128) * OUT + o;
        const float* st = sth + hc * 128;
        float acc = 0.f;
        #pragma unroll 8
        for (int k = 0; k < 128; ++k)
            acc += st[k] * (pw[(size_t)k * OUT] + pd[(size_t)k * OUT]);
        lds[L_BUF + hc * 128 + o] = acc;
    }
    __syncthreads();
    // stats (tid<128, two waves)
    if (tid < 128) {
        const int o = tid;
        const float zo = lds[L_BUF + o] + lds[L_BUF + 128 + o]
                       + lds[L_BUF + 256 + o] + lds[L_BUF + 384 + o]
                       + bias1[o] + db1[b * OUT + o];
        const float tr = ut[b * OUT + o];
        float a = zo * zo, c2 = tr * tr, d = tr * zo;
        for (int off = 32; off; off >>= 1) {
            a  += __shfl_xor(a,  off, 64);
            c2 += __shfl_xor(c2, off, 64);
            d  += __shfl_xor(d,  off, 64);
        }
        const int wv = tid >> 6;
        if ((tid & 63) == 0) { sred[wv*3] = a; sred[wv*3+1] = c2; sred[wv*3+2] = d; }
        sg2[o] = zo;                       // stash zo
    }
    __syncthreads();
    const float l2  = sred[0] + sred[3];                 // squared norm (as in source)
    const float ntv = fmaxf(sqrtf(sred[1] + sred[4]), 1e-12f);
    const float tdot = (sred[2] + sred[5]) / ntv;
    const float sc = 2.0f * tdot / (l2 * l2);
    if (tid < 128) {
        const int o = tid;
        const float zo = sg2[o];
        const float tr = ut[b * OUT + o];
        const float g2 = -(tr / ntv) / l2 + sc * zo;
        sg2[o] = g2;
        out[O_L2N + b * OUT + o] = zo / l2;
        out[O_DB1 + b * OUT + o] = db1[b * OUT + o] - LR * g2;
    }
    __syncthreads();
    // bwd: wave wv owns 64 h rows, lane owns 2 o
    {
        const int wv = tid >> 6, lane = tid & 63, o2 = lane * 2;
        const float g2x = sg2[o2], g2y = sg2[o2 + 1];
        for (int i = 0; i < 64; ++i) {
            const int h = wv * 64 + i;
            const size_t idx = ((size_t)b * HID + h) * OUT + o2;
            const float2 dw = *(const float2*)(dW1 + idx);
            const float2 w1 = *(const float2*)(W1 + (size_t)h * OUT + o2);
            float part = g2x * (w1.x + dw.x) + g2y * (w1.y + dw.y);
            for (int off = 32; off; off >>= 1) part += __shfl_xor(part, off, 64);
            const float th = sth[h];
            vf2 nd;
            nd.x = dw.x - LR * th * g2x;
            nd.y = dw.y - LR * th * g2y;
            __builtin_nontemporal_store(nd, (vf2*)(out + O_DW1 + idx));
            if (lane == 0) {
                const float gbv = (1.f - th * th) * part;
                gbw[(size_t)b * HID + h] = gbv;
                out[O_DB0 + b * HID + h] = db0[b * HID + h] - LR * gbv;
            }
        }
    }
    __syncthreads();
    __threadfence();
    if (tid == 0) {
        const int pos = __hip_atomic_fetch_add(&q->reserve, 1, RX, SCP);
        __hip_atomic_store(&q->list[pos], b + 1, RL, SCP);
        __hip_atomic_fetch_add(&q->tail, 1, RL, SCP);
    }
}

__global__ __launch_bounds__(NTHR, 2)
void k_mega(const float* x, const float* ut, const float* W0, const float* bias0,
            const float* W1, const float* bias1, const float* dW0, const float* db0,
            const float* dW1, const float* db1, float* out,
            float* zpart, float* gbw, int* qmem) {
    __shared__ float lds[L_TOT];
    __shared__ int cmd[2];
    Q* q = (Q*)qmem;
    const int bid = blockIdx.x, tid = threadIdx.x;

    // dedicated compute blocks: one sample each, then join streaming
    if (bid < NCOMP) {
        if (tid == 0) {
            while (__hip_atomic_load(&q->zcnt[bid], AQ, SCP) < 8)
                __builtin_amdgcn_s_sleep(8);
        }
        __syncthreads();
        do_compute(bid, ut, bias0, W1, bias1, db0, dW1, db1,
                   zpart, gbw, out, q, lds, tid);
    }

    // streamer loop: prefer ready upd0 (hot), else fwd1, else wait/exit
    for (;;) {
        __syncthreads();
        if (tid == 0) {
            int kind = 3, arg = 0;
            for (;;) {
                int c = __hip_atomic_load(&q->upd_claim, RX, SCP);
                const int t = __hip_atomic_load(&q->tail, AQ, SCP);
                int lim = t * 8; if (lim > 512) lim = 512;
                if (c < lim) {
                    if (__hip_atomic_compare_exchange_strong(&q->upd_claim, &c, c + 1,
                                                             RX, RX, SCP)) {
                        int bb;
                        while ((bb = __hip_atomic_load(&q->list[c >> 3], AQ, SCP)) == 0)
                            __builtin_amdgcn_s_sleep(2);
                        kind = 1; arg = ((bb - 1) << 3) | (c & 7);
                        break;
                    }
                    continue;                       // CAS lost, retry
                }
                int f = __hip_atomic_load(&q->fwd_claim, RX, SCP);
                if (f < 512) {
                    f = __hip_atomic_fetch_add(&q->fwd_claim, 1, RX, SCP);
                    if (f < 512) { kind = 2; arg = f; break; }
                    continue;
                }
                if (__hip_atomic_load(&q->upd_claim, RX, SCP) >= 512) { kind = 3; break; }
                __builtin_amdgcn_s_sleep(16);       // wait for more ready samples
            }
            cmd[0] = kind; cmd[1] = arg;
        }
        __syncthreads();
        const int kind = cmd[0], arg = cmd[1];
        if (kind == 3) break;
        if (kind == 1) do_upd(arg >> 3, arg & 7, x, dW0, gbw, out + O_DW0, lds, tid);
        else           do_fwd1(arg, x, W0, dW0, zpart, q, lds, tid);
    }
}

// ===================== fallback (proven ~162 us) =====================

__global__ void k_fwd1f(const float* __restrict__ x, const float* __restrict__ W0,
                        const float* __restrict__ dW0, float* __restrict__ zp) {
    const int b = blockIdx.x;
    const int q0 = blockIdx.y * (IN / FQC);
    const int h = threadIdx.x * 4;
    const float* xr = x + b * IN;
    float4 acc = make_float4(0.f, 0.f, 0.f, 0.f);
    for (int qi = 0; qi < IN / FQC; ++qi) {
        const int q = q0 + qi;
        const float xv = xr[q];
        const float4 w0 = *(const float4*)(W0 + q * HID + h);
        const float4 dw = *(const float4*)(dW0 + ((size_t)(b * IN + q)) * HID + h);
        acc.x += xv * (w0.x + dw.x);
        acc.y += xv * (w0.y + dw.y);
        acc.z += xv * (w0.z + dw.z);
        acc.w += xv * (w0.w + dw.w);
    }
    *(float4*)(zp + (b * FQC + blockIdx.y) * HID + h) = acc;
}

__global__ void k_fwd2f(const float* __restrict__ zp, const float* __restrict__ b0,
                        const float* __restrict__ db0, const float* __restrict__ W1,
                        const float* __restrict__ dW1, float* __restrict__ tanhv,
                        float* __restrict__ zop) {
    const int b = blockIdx.x;
    const int h0 = blockIdx.y * 64;
    const int tid = threadIdx.x;
    __shared__ float sth[64];
    if (tid < 64) {
        const int h = h0 + tid;
        float zsum = 0.f;
        #pragma unroll
        for (int qc = 0; qc < FQC; ++qc) zsum += zp[(b * FQC + qc) * HID + h];
        const float th = tanhf(zsum + b0[h] + db0[b * HID + h]);
        tanhv[b * HID + h] = th;
        sth[tid] = th;
    }
    __syncthreads();
    const int o = tid;
    float acc = 0.f;
    #pragma unroll 8
    for (int hi = 0; hi < 64; ++hi) {
        const int h = h0 + hi;
        acc += sth[hi] * (W1[h * OUT + o] + dW1[(b * HID + h) * OUT + o]);
    }
    zop[(b * 8 + blockIdx.y) * OUT + o] = acc;
}

__global__ void k_bwd1f(const float* __restrict__ zop, const float* __restrict__ b1,
                        const float* __restrict__ db1, const float* __restrict__ ut,
                        const float* __restrict__ W1, const float* __restrict__ dW1,
                        const float* __restrict__ tanhv, const float* __restrict__ db0,
                        float* __restrict__ out_l2n, float* __restrict__ out_db1,
                        float* __restrict__ out_dW1, float* __restrict__ out_db0,
                        float* __restrict__ gb) {
    const int b = blockIdx.x;
    const int w = threadIdx.x >> 6;
    const int lane = threadIdx.x & 63;
    const int o2 = lane * 2;
    float2 zo;
    zo.x = b1[o2]     + db1[b * OUT + o2];
    zo.y = b1[o2 + 1] + db1[b * OUT + o2 + 1];
    #pragma unroll
    for (int c = 0; c < 8; ++c) {
        const float2 zp2 = *(const float2*)(zop + (b * 8 + c) * OUT + o2);
        zo.x += zp2.x; zo.y += zp2.y;
    }
    const float2 tr = *(const float2*)(ut + b * OUT + o2);
    float a = zo.x * zo.x + zo.y * zo.y;
    float c2 = tr.x * tr.x + tr.y * tr.y;
    float d  = tr.x * zo.x + tr.y * zo.y;
    for (int off = 32; off; off >>= 1) {
        a  += __shfl_xor(a,  off, 64);
        c2 += __shfl_xor(c2, off, 64);
        d  += __shfl_xor(d,  off, 64);
    }
    const float l2 = a;
    const float nt = fmaxf(sqrtf(c2), 1e-12f);
    const float tdot = d / nt;
    const float s = 2.0f * tdot / (l2 * l2);
    float2 g2;
    g2.x = -(tr.x / nt) / l2 + s * zo.x;
    g2.y = -(tr.y / nt) / l2 + s * zo.y;
    if (blockIdx.y == 0 && w == 0) {
        *(float2*)(out_l2n + b * OUT + o2) = make_float2(zo.x / l2, zo.y / l2);
        *(float2*)(out_db1 + b * OUT + o2) =
            make_float2(db1[b * OUT + o2] - LR * g2.x, db1[b * OUT + o2 + 1] - LR * g2.y);
    }
    for (int i = 0; i < 16; ++i) {
        const int h = blockIdx.y * 64 + w * 16 + i;
        const int idx = (b * HID + h) * OUT + o2;
        const float2 dw = *(const float2*)(dW1 + idx);
        const float2 w1 = *(const float2*)(W1 + h * OUT + o2);
        float part = g2.x * (w1.x + dw.x) + g2.y * (w1.y + dw.y);
        for (int off = 32; off; off >>= 1) part += __shfl_xor(part, off, 64);
        const float th = tanhv[b * HID + h];
        vf2 nd;
        nd.x = dw.x - LR * th * g2.x;
        nd.y = dw.y - LR * th * g2.y;
        __builtin_nontemporal_store(nd, (vf2*)(out_dW1 + idx));
        if (lane == 0) {
            const float gbv = (1.f - th * th) * part;
            gb[b * HID + h] = gbv;
            out_db0[b * HID + h] = db0[b * HID + h] - LR * gbv;
        }
    }
}

__global__ void k_upd0f(const float* __restrict__ dW0, const float* __restrict__ x,
                        const float* __restrict__ gb, float* __restrict__ out_dW0) {
    const int n4 = B * IN * HID / 4;
    const int stride = gridDim.x * blockDim.x;
    for (int i = blockIdx.x * blockDim.x + threadIdx.x; i < n4; i += stride) {
        const int j = n4 - 1 - i;
        const int h4 = j & (HID / 4 - 1);
        const int rest = j >> 7;
        const int q = rest & (IN - 1);
        const int b = rest >> 11;
        const float4 dw = ((const float4*)dW0)[j];
        const float xv = x[b * IN + q];
        const float4 g = *(const float4*)(gb + b * HID + h4 * 4);
        vf4 o;
        o.x = dw.x - LR * xv * g.x;
        o.y = dw.y - LR * xv * g.y;
        o.z = dw.z - LR * xv * g.z;
        o.w = dw.w - LR * xv * g.w;
        __builtin_nontemporal_store(o, (vf4*)out_dW0 + j);
    }
}

extern "C" void kernel_launch(void* const* d_in, const int* in_sizes, int n_in,
                              void* d_out, int out_size, void* d_ws, size_t ws_size,
                              hipStream_t stream) {
    (void)in_sizes; (void)n_in; (void)out_size; (void)ws_size;
    const float* x   = (const float*)d_in[0];
    const float* ut  = (const float*)d_in[1];
    const float* W0  = (const float*)d_in[2];
    const float* b0  = (const float*)d_in[3];
    const float* W1  = (const float*)d_in[4];
    const float* b1  = (const float*)d_in[5];
    const float* dW0 = (const float*)d_in[6];
    const float* db0 = (const float*)d_in[7];
    const float* dW1 = (const float*)d_in[8];
    const float* db1 = (const float*)d_in[9];

    float* ws  = (float*)d_ws;
    float* out = (float*)d_out;
    float* zpart = ws + WS_ZPART;
    float* gbw   = ws + WS_GBW;
    int*   qmem  = (int*)(ws + WS_Q);

    // zero the queue state every replay (graph-capturable)
    hipMemsetAsync(qmem, 0, sizeof(Q), stream);

    void* args[] = {(void*)&x, (void*)&ut, (void*)&W0, (void*)&b0, (void*)&W1,
                    (void*)&b1, (void*)&dW0, (void*)&db0, (void*)&dW1, (void*)&db1,
                    (void*)&out, (void*)&zpart, (void*)&gbw, (void*)&qmem};
    hipError_t err = hipLaunchCooperativeKernel((void*)k_mega, dim3(NBLK), dim3(NTHR),
                                                args, 0, stream);
    if (err != hipSuccess) {
        (void)hipGetLastError();
        k_fwd1f<<<dim3(B, FQC), 128, 0, stream>>>(x, W0, dW0, ws + FWS_ZP);
        k_fwd2f<<<dim3(B, 8), 128, 0, stream>>>(ws + FWS_ZP, b0, db0, W1, dW1,
                                                ws + FWS_TANH, ws + FWS_ZOP);
        k_bwd1f<<<dim3(B, 8), 256, 0, stream>>>(ws + FWS_ZOP, b1, db1, ut, W1, dW1,
                                                ws + FWS_TANH, db0,
                                                out + O_L2N, out + O_DB1,
                                                out + O_DW1, out + O_DB0, ws + FWS_GB);
        k_upd0f<<<dim3(4096), 256, 0, stream>>>(dW0, x, ws + FWS_GB, out + O_DW0);
    }
}

// Round 13
// 548.748 us; speedup vs baseline: 3.1480x; 3.1480x over previous
//
#include <hip/hip_runtime.h>
#include <math.h>

#define LR 0.001f

// Sizes
#define B   64
#define IN  2048
#define HID 512
#define OUT 128
#define NBLK 448
#define NTHR 256
#define NF   256         // fwd1 streamer blocks
#define NU   128         // upd0 streamer blocks
// C team: 64 blocks (bid 384..447)

#define AQ __ATOMIC_ACQUIRE
#define RL __ATOMIC_RELEASE
#define SCP __HIP_MEMORY_SCOPE_AGENT

typedef float vf2 __attribute__((ext_vector_type(2)));
typedef float vf4 __attribute__((ext_vector_type(4)));

// coop ws layout (floats)
#define WS_ZPART 0                        // [64][8][512] = 262144
#define WS_GBW   (WS_ZPART + B*8*HID)     // [64][512]    = 32768
#define WS_FLAGS (WS_GBW + B*HID)         // zcnt[64], gdone[64] ints
// fallback layout (separate replay path; fully rewritten before reads)
#define FQC    16
#define FWS_ZP    0
#define FWS_TANH  (FWS_ZP + B*FQC*HID)
#define FWS_ZOP   (FWS_TANH + B*HID)
#define FWS_GB    (FWS_ZOP + B*8*OUT)

// out layout (floats)
#define O_L2N   0
#define O_DW0   (B*OUT)
#define O_DB0   (O_DW0 + B*IN*HID)
#define O_DW1   (O_DB0 + B*HID)
#define O_DB1   (O_DW1 + B*HID*OUT)

// LDS (floats): ldsx[256] | buf[1024]  (C reuses: sth[512]|red[256]|sg2[128]|sred[8])
#define L_X    0
#define L_BUF  256
#define L_TOT  1280

__device__ __forceinline__ void waitge(const int* p, int val) {
    while (__hip_atomic_load(p, AQ, SCP) < val) __builtin_amdgcn_s_sleep(4);
}

// ---- fwd1 item (b, s): z-partials over 256 q rows; 256 threads ----
__device__ __forceinline__ void do_fwd1(int b, int s, const float* __restrict__ x,
                                        const float* __restrict__ W0,
                                        const float* __restrict__ dW0,
                                        float* __restrict__ zpart, int* zcnt,
                                        float* lds, int tid) {
    const int q0 = s * 256;
    __syncthreads();                       // LDS reuse fence
    lds[L_X + tid] = x[b * IN + q0 + tid];
    __syncthreads();
    const int sub = tid >> 7;              // 0..1, 128 q each
    const int h = (tid & 127) << 2;
    const float* pW = W0 + (size_t)(q0 + sub * 128) * HID + h;
    const float* pD = dW0 + ((size_t)b * IN + q0 + sub * 128) * HID + h;
    const float* xs = lds + L_X + sub * 128;
    float4 a0 = make_float4(0.f, 0.f, 0.f, 0.f);
    float4 a1 = make_float4(0.f, 0.f, 0.f, 0.f);
    #pragma unroll 4
    for (int qi = 0; qi < 64; ++qi) {
        const float xa = xs[qi];
        const float xb = xs[qi + 64];
        const float4 wa = *(const float4*)(pW + (size_t)qi * HID);
        const float4 da = *(const float4*)(pD + (size_t)qi * HID);
        const float4 wb = *(const float4*)(pW + (size_t)(qi + 64) * HID);
        const float4 db_ = *(const float4*)(pD + (size_t)(qi + 64) * HID);
        a0.x += xa * (wa.x + da.x);  a0.y += xa * (wa.y + da.y);
        a0.z += xa * (wa.z + da.z);  a0.w += xa * (wa.w + da.w);
        a1.x += xb * (wb.x + db_.x); a1.y += xb * (wb.y + db_.y);
        a1.z += xb * (wb.z + db_.z); a1.w += xb * (wb.w + db_.w);
    }
    a0.x += a1.x; a0.y += a1.y; a0.z += a1.z; a0.w += a1.w;
    *(float4*)(lds + L_BUF + sub * 512 + h) = a0;
    __syncthreads();
    if (sub == 0) {
        const float4 b1v = *(float4*)(lds + L_BUF + 512 + h);
        a0.x += b1v.x; a0.y += b1v.y; a0.z += b1v.z; a0.w += b1v.w;
        *(float4*)(zpart + ((size_t)b * 8 + s) * HID + h) = a0;
    }
    __syncthreads();
    __threadfence();
    if (tid == 0) __hip_atomic_fetch_add(&zcnt[b], 1, RL, SCP);
}

// ---- upd0 item (b, s): new_dW0 slab (reads L3-hot, NT writes) ----
__device__ __forceinline__ void do_upd(int b, int s, const float* __restrict__ x,
                                       const float* __restrict__ dW0,
                                       const float* __restrict__ gbw,
                                       float* __restrict__ out_dW0,
                                       float* lds, int tid) {
    __syncthreads();
    lds[L_X + tid] = x[b * IN + s * 256 + tid];
    lds[L_BUF + tid] = gbw[(size_t)b * HID + tid];
    lds[L_BUF + 256 + tid] = gbw[(size_t)b * HID + 256 + tid];
    __syncthreads();
    const size_t base4 = ((size_t)b * IN + s * 256) * (HID / 4);
    const float4* src = (const float4*)dW0;
    vf4* dst = (vf4*)out_dW0;
    #pragma unroll 8
    for (int it = 0; it < 128; ++it) {
        const int i = it * NTHR + tid;
        const int ql = i >> 7, h4 = i & 127;
        const float4 dw = src[base4 + i];
        const float xv = lds[L_X + ql];
        const float4 g = *(const float4*)&lds[L_BUF + h4 * 4];
        vf4 o4;
        o4.x = dw.x - LR * xv * g.x;
        o4.y = dw.y - LR * xv * g.y;
        o4.z = dw.z - LR * xv * g.z;
        o4.w = dw.w - LR * xv * g.w;
        __builtin_nontemporal_store(o4, dst + base4 + i);
    }
}

// ---- compute for one sample: tanh + zo + stats + g2 + bwd1 + gb ----
__device__ __forceinline__ void do_compute(int b, const float* __restrict__ ut,
                                           const float* __restrict__ bias0,
                                           const float* __restrict__ W1,
                                           const float* __restrict__ bias1,
                                           const float* __restrict__ db0,
                                           const float* __restrict__ dW1,
                                           const float* __restrict__ db1,
                                           const float* __restrict__ zpart,
                                           float* __restrict__ gbw,
                                           float* __restrict__ out,
                                           int* gdone, float* lds, int tid) {
    float* sth = lds;               // 512
    float* red = lds + 512;         // 256
    float* sg2 = lds + 768;         // 128
    float* sred = lds + 896;        // 8
    // tanh(z + b0 + db0): 2 h per thread
    #pragma unroll
    for (int r = 0; r < 2; ++r) {
        const int h = tid + r * NTHR;
        float zs = 0.f;
        #pragma unroll
        for (int k = 0; k < 8; ++k) zs += zpart[((size_t)b * 8 + k) * HID + h];
        sth[h] = tanhf(zs + bias0[h] + db0[b * HID + h]);
    }
    __syncthreads();
    // zo partials: o = tid&127, hc = tid>>7 owns 256 h rows
    {
        const int o = tid & 127, hc = tid >> 7;
        const float* pw = W1 + (size_t)(hc * 256) * OUT + o;
        const float* pd = dW1 + ((size_t)b * HID + hc * 256) * OUT + o;
        const float* st = sth + hc * 256;
        float acc = 0.f;
        #pragma unroll 8
        for (int k = 0; k < 256; ++k)
            acc += st[k] * (pw[(size_t)k * OUT] + pd[(size_t)k * OUT]);
        red[hc * 128 + o] = acc;
    }
    __syncthreads();
    if (tid < 128) {
        const int o = tid;
        const float zo = red[o] + red[128 + o] + bias1[o] + db1[b * OUT + o];
        const float tr = ut[b * OUT + o];
        float a = zo * zo, c2 = tr * tr, d = tr * zo;
        for (int off = 32; off; off >>= 1) {
            a  += __shfl_xor(a,  off, 64);
            c2 += __shfl_xor(c2, off, 64);
            d  += __shfl_xor(d,  off, 64);
        }
        const int wv = tid >> 6;
        if ((tid & 63) == 0) { sred[wv*3] = a; sred[wv*3+1] = c2; sred[wv*3+2] = d; }
        sg2[o] = zo;
    }
    __syncthreads();
    const float l2  = sred[0] + sred[3];                 // squared norm (as in source)
    const float ntv = fmaxf(sqrtf(sred[1] + sred[4]), 1e-12f);
    const float tdot = (sred[2] + sred[5]) / ntv;
    const float sc = 2.0f * tdot / (l2 * l2);
    if (tid < 128) {
        const int o = tid;
        const float zo = sg2[o];
        const float tr = ut[b * OUT + o];
        const float g2 = -(tr / ntv) / l2 + sc * zo;
        sg2[o] = g2;
        out[O_L2N + b * OUT + o] = zo / l2;
        out[O_DB1 + b * OUT + o] = db1[b * OUT + o] - LR * g2;
    }
    __syncthreads();
    // bwd: 4 waves x 128 h rows, lane owns 2 o; coalesced float2 rows
    {
        const int wv = tid >> 6, lane = tid & 63, o2 = lane * 2;
        const float g2x = sg2[o2], g2y = sg2[o2 + 1];
        for (int i = 0; i < 128; ++i) {
            const int h = wv * 128 + i;
            const size_t idx = ((size_t)b * HID + h) * OUT + o2;
            const float2 dw = *(const float2*)(dW1 + idx);
            const float2 w1 = *(const float2*)(W1 + (size_t)h * OUT + o2);
            float part = g2x * (w1.x + dw.x) + g2y * (w1.y + dw.y);
            for (int off = 32; off; off >>= 1) part += __shfl_xor(part, off, 64);
            const float th = sth[h];
            vf2 nd;
            nd.x = dw.x - LR * th * g2x;
            nd.y = dw.y - LR * th * g2y;
            __builtin_nontemporal_store(nd, (vf2*)(out + O_DW1 + idx));
            if (lane == 0) {
                const float gbv = (1.f - th * th) * part;
                gbw[(size_t)b * HID + h] = gbv;
                out[O_DB0 + b * HID + h] = db0[b * HID + h] - LR * gbv;
            }
        }
    }
    __syncthreads();
    __threadfence();
    if (tid == 0) __hip_atomic_store(&gdone[b], 1, RL, SCP);
}

__global__ __launch_bounds__(NTHR, 2)
void k_mega(const float* x, const float* ut, const float* W0, const float* bias0,
            const float* W1, const float* bias1, const float* dW0, const float* db0,
            const float* dW1, const float* db1, float* out,
            float* zpart, float* gbw, int* flags) {
    __shared__ float lds[L_TOT];
    int* zcnt = flags;
    int* gdone = flags + B;
    const int bid = blockIdx.x, tid = threadIdx.x;

    if (bid < NF) {
        // F team: items bid, bid+256 (samples 0..31 then 32..63, in order)
        #pragma unroll
        for (int k = 0; k < 2; ++k) {
            const int j = bid + NF * k;
            do_fwd1(j >> 3, j & 7, x, W0, dW0, zpart, zcnt, lds, tid);
        }
    } else if (bid < NF + NU) {
        // U team: items u+128k => (b = m+16k, s) for u = 8m+s
        const int u = bid - NF;
        #pragma unroll
        for (int k = 0; k < 4; ++k) {
            const int j = u + NU * k;
            const int b = j >> 3, s = j & 7;
            if (tid == 0) waitge(&gdone[b], 1);
            __syncthreads();
            do_upd(b, s, x, dW0, gbw, out + O_DW0, lds, tid);
        }
    } else {
        // C team: one sample per block
        const int b = bid - (NF + NU);
        if (tid == 0) waitge(&zcnt[b], 8);
        __syncthreads();
        do_compute(b, ut, bias0, W1, bias1, db0, dW1, db1,
                   zpart, gbw, out, gdone, lds, tid);
    }
}

// ===================== fallback (proven ~162 us) =====================

__global__ void k_fwd1f(const float* __restrict__ x, const float* __restrict__ W0,
                        const float* __restrict__ dW0, float* __restrict__ zp) {
    const int b = blockIdx.x;
    const int q0 = blockIdx.y * (IN / FQC);
    const int h = threadIdx.x * 4;
    const float* xr = x + b * IN;
    float4 acc = make_float4(0.f, 0.f, 0.f, 0.f);
    for (int qi = 0; qi < IN / FQC; ++qi) {
        const int q = q0 + qi;
        const float xv = xr[q];
        const float4 w0 = *(const float4*)(W0 + q * HID + h);
        const float4 dw = *(const float4*)(dW0 + ((size_t)(b * IN + q)) * HID + h);
        acc.x += xv * (w0.x + dw.x);
        acc.y += xv * (w0.y + dw.y);
        acc.z += xv * (w0.z + dw.z);
        acc.w += xv * (w0.w + dw.w);
    }
    *(float4*)(zp + (b * FQC + blockIdx.y) * HID + h) = acc;
}

__global__ void k_fwd2f(const float* __restrict__ zp, const float* __restrict__ b0,
                        const float* __restrict__ db0, const float* __restrict__ W1,
                        const float* __restrict__ dW1, float* __restrict__ tanhv,
                        float* __restrict__ zop) {
    const int b = blockIdx.x;
    const int h0 = blockIdx.y * 64;
    const int tid = threadIdx.x;
    __shared__ float sth[64];
    if (tid < 64) {
        const int h = h0 + tid;
        float zsum = 0.f;
        #pragma unroll
        for (int qc = 0; qc < FQC; ++qc) zsum += zp[(b * FQC + qc) * HID + h];
        const float th = tanhf(zsum + b0[h] + db0[b * HID + h]);
        tanhv[b * HID + h] = th;
        sth[tid] = th;
    }
    __syncthreads();
    const int o = tid;
    float acc = 0.f;
    #pragma unroll 8
    for (int hi = 0; hi < 64; ++hi) {
        const int h = h0 + hi;
        acc += sth[hi] * (W1[h * OUT + o] + dW1[(b * HID + h) * OUT + o]);
    }
    zop[(b * 8 + blockIdx.y) * OUT + o] = acc;
}

__global__ void k_bwd1f(const float* __restrict__ zop, const float* __restrict__ b1,
                        const float* __restrict__ db1, const float* __restrict__ ut,
                        const float* __restrict__ W1, const float* __restrict__ dW1,
                        const float* __restrict__ tanhv, const float* __restrict__ db0,
                        float* __restrict__ out_l2n, float* __restrict__ out_db1,
                        float* __restrict__ out_dW1, float* __restrict__ out_db0,
                        float* __restrict__ gb) {
    const int b = blockIdx.x;
    const int w = threadIdx.x >> 6;
    const int lane = threadIdx.x & 63;
    const int o2 = lane * 2;
    float2 zo;
    zo.x = b1[o2]     + db1[b * OUT + o2];
    zo.y = b1[o2 + 1] + db1[b * OUT + o2 + 1];
    #pragma unroll
    for (int c = 0; c < 8; ++c) {
        const float2 zp2 = *(const float2*)(zop + (b * 8 + c) * OUT + o2);
        zo.x += zp2.x; zo.y += zp2.y;
    }
    const float2 tr = *(const float2*)(ut + b * OUT + o2);
    float a = zo.x * zo.x + zo.y * zo.y;
    float c2 = tr.x * tr.x + tr.y * tr.y;
    float d  = tr.x * zo.x + tr.y * zo.y;
    for (int off = 32; off; off >>= 1) {
        a  += __shfl_xor(a,  off, 64);
        c2 += __shfl_xor(c2, off, 64);
        d  += __shfl_xor(d,  off, 64);
    }
    const float l2 = a;
    const float nt = fmaxf(sqrtf(c2), 1e-12f);
    const float tdot = d / nt;
    const float s = 2.0f * tdot / (l2 * l2);
    float2 g2;
    g2.x = -(tr.x / nt) / l2 + s * zo.x;
    g2.y = -(tr.y / nt) / l2 + s * zo.y;
    if (blockIdx.y == 0 && w == 0) {
        *(float2*)(out_l2n + b * OUT + o2) = make_float2(zo.x / l2, zo.y / l2);
        *(float2*)(out_db1 + b * OUT + o2) =
            make_float2(db1[b * OUT + o2] - LR * g2.x, db1[b * OUT + o2 + 1] - LR * g2.y);
    }
    for (int i = 0; i < 16; ++i) {
        const int h = blockIdx.y * 64 + w * 16 + i;
        const int idx = (b * HID + h) * OUT + o2;
        const float2 dw = *(const float2*)(dW1 + idx);
        const float2 w1 = *(const float2*)(W1 + h * OUT + o2);
        float part = g2.x * (w1.x + dw.x) + g2.y * (w1.y + dw.y);
        for (int off = 32; off; off >>= 1) part += __shfl_xor(part, off, 64);
        const float th = tanhv[b * HID + h];
        vf2 nd;
        nd.x = dw.x - LR * th * g2.x;
        nd.y = dw.y - LR * th * g2.y;
        __builtin_nontemporal_store(nd, (vf2*)(out_dW1 + idx));
        if (lane == 0) {
            const float gbv = (1.f - th * th) * part;
            gb[b * HID + h] = gbv;
            out_db0[b * HID + h] = db0[b * HID + h] - LR * gbv;
        }
    }
}

__global__ void k_upd0f(const float* __restrict__ dW0, const float* __restrict__ x,
                        const float* __restrict__ gb, float* __restrict__ out_dW0) {
    const int n4 = B * IN * HID / 4;
    const int stride = gridDim.x * blockDim.x;
    for (int i = blockIdx.x * blockDim.x + threadIdx.x; i < n4; i += stride) {
        const int j = n4 - 1 - i;
        const int h4 = j & (HID / 4 - 1);
        const int rest = j >> 7;
        const int q = rest & (IN - 1);
        const int b = rest >> 11;
        const float4 dw = ((const float4*)dW0)[j];
        const float xv = x[b * IN + q];
        const float4 g = *(const float4*)(gb + b * HID + h4 * 4);
        vf4 o;
        o.x = dw.x - LR * xv * g.x;
        o.y = dw.y - LR * xv * g.y;
        o.z = dw.z - LR * xv * g.z;
        o.w = dw.w - LR * xv * g.w;
        __builtin_nontemporal_store(o, (vf4*)out_dW0 + j);
    }
}

extern "C" void kernel_launch(void* const* d_in, const int* in_sizes, int n_in,
                              void* d_out, int out_size, void* d_ws, size_t ws_size,
                              hipStream_t stream) {
    (void)in_sizes; (void)n_in; (void)out_size; (void)ws_size;
    const float* x   = (const float*)d_in[0];
    const float* ut  = (const float*)d_in[1];
    const float* W0  = (const float*)d_in[2];
    const float* b0  = (const float*)d_in[3];
    const float* W1  = (const float*)d_in[4];
    const float* b1  = (const float*)d_in[5];
    const float* dW0 = (const float*)d_in[6];
    const float* db0 = (const float*)d_in[7];
    const float* dW1 = (const float*)d_in[8];
    const float* db1 = (const float*)d_in[9];

    float* ws  = (float*)d_ws;
    float* out = (float*)d_out;
    float* zpart = ws + WS_ZPART;
    float* gbw   = ws + WS_GBW;
    int*   flags = (int*)(ws + WS_FLAGS);

    // zero ready flags every replay (graph-capturable)
    hipMemsetAsync(flags, 0, 2 * B * sizeof(int), stream);

    void* args[] = {(void*)&x, (void*)&ut, (void*)&W0, (void*)&b0, (void*)&W1,
                    (void*)&b1, (void*)&dW0, (void*)&db0, (void*)&dW1, (void*)&db1,
                    (void*)&out, (void*)&zpart, (void*)&gbw, (void*)&flags};
    hipError_t err = hipLaunchCooperativeKernel((void*)k_mega, dim3(NBLK), dim3(NTHR),
                                                args, 0, stream);
    if (err != hipSuccess) {
        (void)hipGetLastError();
        k_fwd1f<<<dim3(B, FQC), 128, 0, stream>>>(x, W0, dW0, ws + FWS_ZP);
        k_fwd2f<<<dim3(B, 8), 128, 0, stream>>>(ws + FWS_ZP, b0, db0, W1, dW1,
                                                ws + FWS_TANH, ws + FWS_ZOP);
        k_bwd1f<<<dim3(B, 8), 256, 0, stream>>>(ws + FWS_ZOP, b1, db1, ut, W1, dW1,
                                                ws + FWS_TANH, db0,
                                                out + O_L2N, out + O_DB1,
                                                out + O_DW1, out + O_DB0, ws + FWS_GB);
        k_upd0f<<<dim3(4096), 256, 0, stream>>>(dW0, x, ws + FWS_GB, out + O_DW0);
    }
}